// Round 5
// baseline (275.008 us; speedup 1.0000x reference)
//
#include <hip/hip_runtime.h>
#include <hip/hip_bf16.h>

typedef __attribute__((ext_vector_type(8))) short short8;
typedef __attribute__((ext_vector_type(4))) float floatx4;

#define B_SZ   32
#define L_IN   8192
#define C_INCH 64
#define KW     3
#define F_OUT  128
#define L_OUT  (L_IN - KW + 1)   // 8190
#define KDIM   (KW * C_INCH)     // 192

#define TILE_L  64
#define AROWS   (TILE_L + 2)     // 66
#define ASTRIDE 72               // 64 + 8 pad; rows 16B-aligned, 2-way-max (free) b128 pattern

// packed fp32x2 -> bf16x2 (RNE, emits v_cvt_pk_bf16_f32), low short = first arg
__device__ __forceinline__ unsigned pk2(float a, float b) {
    __hip_bfloat162 h = __float22bfloat162_rn(make_float2(a, b));
    unsigned u;
    __builtin_memcpy(&u, &h, 4);   // byte copy: legal for non-trivially-copyable, folds away
    return u;
}

// Single kernel, no workspace. Implicit GEMM: M = B*8190 (each A-row is the
// 192 contiguous floats x[b, l:l+3, :]), N = 128, K = 192 (fully resident).
// R5 = R4 with the bit_cast compile fix: x-loads issued wide before anything
// else; bfrag (48 VGPRs) built only after x-loads are in flight, with x
// convert+LDS-write interleaved into the first w batches; packed converts.
__global__ __launch_bounds__(256, 4) void conv1d_mfma(const float* __restrict__ x,
                                                      const float* __restrict__ w,
                                                      const float* __restrict__ bias,
                                                      float* __restrict__ out) {
    __shared__ short a_lds[AROWS * ASTRIDE];  // 9504 B

    const int tid  = threadIdx.x;
    const int b    = blockIdx.y;
    const int l0   = blockIdx.x * TILE_L;
    const int lane = tid & 63;
    const int wave = tid >> 6;
    const int q    = lane >> 4;   // quad 0..3
    const int nl   = lane & 15;

    // ---- 1) issue ALL x-tile loads first (<=3 chunks of 32 B per thread) ----
    float4 xv0[3], xv1[3];
#pragma unroll
    for (int i = 0; i < 3; ++i) {
        int c = tid + 256 * i;
        if (c < AROWS * 8) {
            int p   = c >> 3;          // local row 0..65
            int col = (c & 7) * 8;     // channel 0,8,..,56
            int gl  = l0 + p;
            if (gl < L_IN) {
                const float4* xp =
                    (const float4*)(x + ((size_t)b * L_IN + gl) * C_INCH + col);
                xv0[i] = xp[0];
                xv1[i] = xp[1];
            } else {
                xv0[i] = make_float4(0.f, 0.f, 0.f, 0.f);
                xv1[i] = xv0[i];
            }
        }
    }

    // ---- 2) w -> bfrag (verified layout: lane(nl,q) of n-tile n holds
    // B[k = s*32 + q*8 + j][f = (wave*2+n)*16 + nl], j=0..7; w[k*128+f] fp32),
    // with x convert+LDS-write interleaved into the first 3 batches ----
    short8 bfrag[6][2];
#pragma unroll
    for (int n = 0; n < 2; ++n) {
        const int f = (wave * 2 + n) * 16 + nl;
        const float* __restrict__ wf = w + f;
#pragma unroll
        for (int s = 0; s < 6; ++s) {
            float t[8];
#pragma unroll
            for (int j = 0; j < 8; ++j)
                t[j] = wf[(s * 32 + q * 8 + j) * F_OUT];

            // independent x work while the 8 w-loads are in flight
            const int bi = n * 6 + s;
            if (bi < 3) {
                int c = tid + 256 * bi;
                if (c < AROWS * 8) {
                    int p   = c >> 3;
                    int col = (c & 7) * 8;
                    union { unsigned u[4]; short8 v; } h;
                    h.u[0] = pk2(xv0[bi].x, xv0[bi].y);
                    h.u[1] = pk2(xv0[bi].z, xv0[bi].w);
                    h.u[2] = pk2(xv1[bi].x, xv1[bi].y);
                    h.u[3] = pk2(xv1[bi].z, xv1[bi].w);
                    *(short8*)&a_lds[p * ASTRIDE + col] = h.v;
                }
            }

            union { unsigned u[4]; short8 v; } hb;
            hb.u[0] = pk2(t[0], t[1]);
            hb.u[1] = pk2(t[2], t[3]);
            hb.u[2] = pk2(t[4], t[5]);
            hb.u[3] = pk2(t[6], t[7]);
            bfrag[s][n] = hb.v;
        }
    }

    __syncthreads();

    // ---- 3) K-loop: 6 steps of 32; 4 m-tiles x 2 n-tiles per wave ----
    floatx4 acc[4][2];
#pragma unroll
    for (int m = 0; m < 4; ++m)
#pragma unroll
        for (int n = 0; n < 2; ++n) acc[m][n] = (floatx4){0.f, 0.f, 0.f, 0.f};

#pragma unroll
    for (int s = 0; s < 6; ++s) {
#pragma unroll
        for (int m = 0; m < 4; ++m) {
            short8 af = *(const short8*)&a_lds[(m * 16 + nl + (s >> 1)) * ASTRIDE
                                               + (s & 1) * 32 + q * 8];
#pragma unroll
            for (int n = 0; n < 2; ++n)
                acc[m][n] = __builtin_amdgcn_mfma_f32_16x16x32_bf16(
                    af, bfrag[s][n], acc[m][n], 0, 0, 0);
        }
    }

    // ---- 4) epilogue: C/D layout col(=f within tile)=nl, row = q*4 + r ----
#pragma unroll
    for (int n = 0; n < 2; ++n) {
        const int f  = (wave * 2 + n) * 16 + nl;
        const float bv = bias[f];
#pragma unroll
        for (int m = 0; m < 4; ++m) {
            const int lb = l0 + m * 16 + q * 4;
#pragma unroll
            for (int r = 0; r < 4; ++r) {
                int l = lb + r;
                if (l < L_OUT) {
                    float v = acc[m][n][r] + bv;
                    out[((size_t)b * L_OUT + l) * F_OUT + f] = v > 0.f ? v : 0.f;
                }
            }
        }
    }
}

extern "C" void kernel_launch(void* const* d_in, const int* in_sizes, int n_in,
                              void* d_out, int out_size, void* d_ws, size_t ws_size,
                              hipStream_t stream) {
    const float* x    = (const float*)d_in[0];
    const float* w    = (const float*)d_in[1];
    const float* bias = (const float*)d_in[2];
    float* out        = (float*)d_out;
    (void)d_ws; (void)ws_size;

    conv1d_mfma<<<dim3(L_IN / TILE_L, B_SZ), 256, 0, stream>>>(x, w, bias, out);
}

// Round 6
// 214.378 us; speedup vs baseline: 1.2828x; 1.2828x over previous
//
#include <hip/hip_runtime.h>
#include <hip/hip_bf16.h>

typedef __attribute__((ext_vector_type(8))) short short8;
typedef __attribute__((ext_vector_type(4))) float floatx4;

#define B_SZ   32
#define L_IN   8192
#define C_INCH 64
#define KW     3
#define F_OUT  128
#define L_OUT  (L_IN - KW + 1)   // 8190
#define KDIM   (KW * C_INCH)     // 192

#define TILE_L  64
#define AROWS   (TILE_L + 2)     // 66
#define ASTRIDE 72               // 64 + 8 pad; uniform 8-lanes-per-bank-group b128 pattern
#define TPB     4                // L-tiles per block (w-build amortization factor)
#define NGRID   (B_SZ * (L_IN / TILE_L) / TPB)   // 1024 blocks

// packed fp32x2 -> bf16x2 (RNE, emits v_cvt_pk_bf16_f32)
__device__ __forceinline__ unsigned pk2(float a, float b) {
    __hip_bfloat162 h = __float22bfloat162_rn(make_float2(a, b));
    unsigned u;
    __builtin_memcpy(&u, &h, 4);   // byte copy: legal + folds away
    return u;
}

// Implicit GEMM: M = B*8190 (A-row = 192 contiguous floats x[b, l:l+3, :]),
// N = 128, K = 192 fully resident. R6: persistent blocks over TPB=4 L-tiles:
// bfrag (96 loads + 48 cvt/thread) built ONCE per 4 tiles; x staging
// double-buffered in LDS, next tile's loads issued AFTER the barrier (the
// compiler drains vmcnt at s_barrier) so they hide behind kloop+epilogue.
// NOTE: __launch_bounds__ min-waves stays 3 — (256,4) forced VGPR=64 and
// spilled (R5: FETCH 34->72 MB, WRITE 165->255 MB, dur +37%).
__global__ __launch_bounds__(256, 3) void conv1d_mfma(const float* __restrict__ x,
                                                      const float* __restrict__ w,
                                                      const float* __restrict__ bias,
                                                      float* __restrict__ out) {
    __shared__ short a_lds[2][AROWS * ASTRIDE];  // 2 x 9504 B

    const int tid  = threadIdx.x;
    const int lane = tid & 63;
    const int wave = tid >> 6;
    const int q    = lane >> 4;   // quad 0..3
    const int nl   = lane & 15;

    const int g      = blockIdx.x;
    const int b      = g >> 5;                     // 32 tile-groups per batch row
    const int l_base = (g & 31) * (TPB * TILE_L);  // 256-row span per block

    // ---- B fragments once per block (verified layout: lane(nl,q) of n-tile n
    // holds B[k = s*32 + q*8 + j][f = (wave*2+n)*16 + nl]; w[k*128+f] fp32) ----
    short8 bfrag[6][2];
#pragma unroll
    for (int n = 0; n < 2; ++n) {
        const int f = (wave * 2 + n) * 16 + nl;
        const float* __restrict__ wf = w + f;
#pragma unroll
        for (int s = 0; s < 6; ++s) {
            float t[8];
#pragma unroll
            for (int j = 0; j < 8; ++j)
                t[j] = wf[(s * 32 + q * 8 + j) * F_OUT];
            union { unsigned u[4]; short8 v; } hb;
            hb.u[0] = pk2(t[0], t[1]);
            hb.u[1] = pk2(t[2], t[3]);
            hb.u[2] = pk2(t[4], t[5]);
            hb.u[3] = pk2(t[6], t[7]);
            bfrag[s][n] = hb.v;
        }
    }

    // bias hoisted out of the tile loop
    float bv[2];
#pragma unroll
    for (int n = 0; n < 2; ++n) bv[n] = bias[(wave * 2 + n) * 16 + nl];

    // ---- x-load for tile 0 ----
    float4 xv0[3], xv1[3];
    {
        const int l0 = l_base;
#pragma unroll
        for (int i = 0; i < 3; ++i) {
            int c = tid + 256 * i;
            if (c < AROWS * 8) {
                int p   = c >> 3;
                int col = (c & 7) * 8;
                int gl  = l0 + p;
                if (gl < L_IN) {
                    const float4* xp =
                        (const float4*)(x + ((size_t)b * L_IN + gl) * C_INCH + col);
                    xv0[i] = xp[0];
                    xv1[i] = xp[1];
                } else {
                    xv0[i] = make_float4(0.f, 0.f, 0.f, 0.f);
                    xv1[i] = xv0[i];
                }
            }
        }
    }

#pragma unroll
    for (int t = 0; t < TPB; ++t) {
        short* buf = a_lds[t & 1];

        // ---- convert + stage tile t ----
#pragma unroll
        for (int i = 0; i < 3; ++i) {
            int c = tid + 256 * i;
            if (c < AROWS * 8) {
                int p   = c >> 3;
                int col = (c & 7) * 8;
                union { unsigned u[4]; short8 v; } h;
                h.u[0] = pk2(xv0[i].x, xv0[i].y);
                h.u[1] = pk2(xv0[i].z, xv0[i].w);
                h.u[2] = pk2(xv1[i].x, xv1[i].y);
                h.u[3] = pk2(xv1[i].z, xv1[i].w);
                *(short8*)&buf[p * ASTRIDE + col] = h.v;
            }
        }
        __syncthreads();

        // ---- prefetch tile t+1 (after barrier; hides behind kloop+epilogue) ----
        if (t + 1 < TPB) {
            const int l0n = l_base + (t + 1) * TILE_L;
#pragma unroll
            for (int i = 0; i < 3; ++i) {
                int c = tid + 256 * i;
                if (c < AROWS * 8) {
                    int p   = c >> 3;
                    int col = (c & 7) * 8;
                    int gl  = l0n + p;
                    if (gl < L_IN) {
                        const float4* xp =
                            (const float4*)(x + ((size_t)b * L_IN + gl) * C_INCH + col);
                        xv0[i] = xp[0];
                        xv1[i] = xp[1];
                    } else {
                        xv0[i] = make_float4(0.f, 0.f, 0.f, 0.f);
                        xv1[i] = xv0[i];
                    }
                }
            }
        }

        // ---- K-loop: 6 steps of 32; 4 m-tiles x 2 n-tiles per wave ----
        floatx4 acc[4][2];
#pragma unroll
        for (int m = 0; m < 4; ++m)
#pragma unroll
            for (int n = 0; n < 2; ++n) acc[m][n] = (floatx4){0.f, 0.f, 0.f, 0.f};

#pragma unroll
        for (int s = 0; s < 6; ++s) {
#pragma unroll
            for (int m = 0; m < 4; ++m) {
                short8 af = *(const short8*)&buf[(m * 16 + nl + (s >> 1)) * ASTRIDE
                                                 + (s & 1) * 32 + q * 8];
#pragma unroll
                for (int n = 0; n < 2; ++n)
                    acc[m][n] = __builtin_amdgcn_mfma_f32_16x16x32_bf16(
                        af, bfrag[s][n], acc[m][n], 0, 0, 0);
            }
        }

        // ---- epilogue: C/D layout col(=f within tile)=nl, row = q*4 + r ----
        const int l0 = l_base + t * TILE_L;
#pragma unroll
        for (int n = 0; n < 2; ++n) {
            const int f = (wave * 2 + n) * 16 + nl;
#pragma unroll
            for (int m = 0; m < 4; ++m) {
                const int lb = l0 + m * 16 + q * 4;
#pragma unroll
                for (int r = 0; r < 4; ++r) {
                    int l = lb + r;
                    if (l < L_OUT) {
                        float v = acc[m][n][r] + bv[n];
                        out[((size_t)b * L_OUT + l) * F_OUT + f] = v > 0.f ? v : 0.f;
                    }
                }
            }
        }
    }
}

extern "C" void kernel_launch(void* const* d_in, const int* in_sizes, int n_in,
                              void* d_out, int out_size, void* d_ws, size_t ws_size,
                              hipStream_t stream) {
    const float* x    = (const float*)d_in[0];
    const float* w    = (const float*)d_in[1];
    const float* bias = (const float*)d_in[2];
    float* out        = (float*)d_out;
    (void)d_ws; (void)ws_size;

    conv1d_mfma<<<dim3(NGRID), 256, 0, stream>>>(x, w, bias, out);
}